// Round 11
// baseline (607.264 us; speedup 1.0000x reference)
//
#include <hip/hip_runtime.h>

// SimpleRNN: B=16384, T=2048, I=1, H=20, O=1, fp32.
//
// Round-15. r14 (494 us counter) confirmed the model: ~9.65 wall-cyc per
// SOURCE inst at 1 wave/SIMD; three consecutive on-target predictions.
// Step budget ~60: 8 init-fma + 6 MFMA + 24 act + ~20 pack + ~2 loop.
// This round: VOP3P pk-ization of the remaining scalar pairs (r5 proved
// v2f elementwise ops emit v_pk_*_f32):
//  (a) init: 8 v_fma -> 4 v_pk_fma_f32 (v2f pairs, bit_cast into f32x4 C).
//  (b) act:  8 scalar +1.0 -> 4 v_pk_add_f32 (exp2 results paired).
// Both bit-identical IEEE ops -> absmax stays exactly 0.00390625.
// Step 60 -> 52 src-insts. Rejected alternatives: 32x32 tile (act 2x, C/B
// layout mismatch), 2 waves/SIMD (per-batch insts double, r11), x-in-K-slot
// (init-fma becomes init-mov, no gain), f16 single weights (16x quant risk).
//
//   C = (-2K*W_hh) @ r^T via mfma_f32_16x16x32_bf16 (layout verified r9):
//   C col = lane&15 = batch, row = 4*(lane>>4)+reg == next B fragment
//   in-lane. K-slot map (A,B identical): j<4 -> c=4g+j, j>=4 -> 16+4g+(j-4),
//   c>=20 zero-padded. rc-state folding: state r = rcp(exp2(z)+1); W_hh
//   pre-scaled by -2K, bias = K*(b_ih+b_hh+rowsum(W_hh)), W_ih by K
//   (K = 2*log2(e)); h = 1-2r only in epilogue. Truncation split hi/lo on
//   BOTH weights and state; 3 MFMA terms per tile (AhBh, AlBh, AhBl).
//
// 16 batches/wave -> 65536 threads = 1024 waves = 1 wave/SIMD, full chip.

#define RNN_T 2048
#define RNN_H 20
#define RNN_B 16384
#define NT4   (RNN_T / 4)

typedef float f32x4  __attribute__((ext_vector_type(4)));
typedef float v2f    __attribute__((ext_vector_type(2)));
typedef short bf16x8 __attribute__((ext_vector_type(8)));
typedef int   i32x4  __attribute__((ext_vector_type(4)));

struct p2 { v2f a, b; };   // two aligned f32 pairs == one f32x4

// D = [bf16(b) : bf16(a)] by truncation; a lands in the LOW short (even elem).
__device__ __forceinline__ int pk_trunc(float a, float b) {
    return __builtin_amdgcn_perm(__builtin_bit_cast(int, b),
                                 __builtin_bit_cast(int, a), 0x07060302);
}
__device__ __forceinline__ float trunc_bf(float a) {
    return __builtin_bit_cast(float,
                              (int)(__builtin_bit_cast(int, a) & 0xffff0000));
}
// Recover the two truncated f32 values from a packed [bf16:bf16] word.
__device__ __forceinline__ float lo16f(int w) {
    return __builtin_bit_cast(float, (int)(w << 16));
}
__device__ __forceinline__ float hi16f(int w) {
    return __builtin_bit_cast(float, (int)(w & (int)0xffff0000u));
}

__attribute__((amdgpu_flat_work_group_size(256, 256)))
__global__ void rnn_fwd(const float* __restrict__ x,
                        const float* __restrict__ W_ih,
                        const float* __restrict__ W_hh,
                        const float* __restrict__ b_ih,
                        const float* __restrict__ b_hh,
                        const float* __restrict__ W_fc,
                        const float* __restrict__ b_fc,
                        float* __restrict__ out) {
    const int gid  = blockIdx.x * blockDim.x + threadIdx.x;
    const int lane = threadIdx.x & 63;
    const int wid  = gid >> 6;        // global wave index
    const int B0   = wid * 16;        // this wave's batch block
    const int col  = lane & 15;       // batch slot / A-row m / B-col n
    const int g    = lane >> 4;       // k-block / C-row-block

    const float KS = 2.885390081777927f;  // 2*log2(e)
    const float WS = -2.0f * KS;          // W_hh scale

    // ---- Prologue: A fragments (W_hh * -2K, truncation split hi/lo) ----
    float w1[8], w2[8], l1[8], l2[8];
#pragma unroll
    for (int j = 0; j < 8; ++j) {
        const int c   = (j < 4) ? (4 * g + j) : (16 + 4 * g + (j - 4));
        const float m = (c < RNN_H) ? WS : 0.0f;
        const int cc  = (c < RNN_H) ? c : 0;
        w1[j] = m * W_hh[col * RNN_H + cc];                              // rows 0..15
        w2[j] = (col < 4) ? m * W_hh[(16 + col) * RNN_H + cc] : 0.0f;    // rows 16..19
        l1[j] = w1[j] - trunc_bf(w1[j]);
        l2[j] = w2[j] - trunc_bf(w2[j]);
    }
    i32x4 a1h, a1l, a2h, a2l;
    a1h.x = pk_trunc(w1[0], w1[1]); a1h.y = pk_trunc(w1[2], w1[3]);
    a1h.z = pk_trunc(w1[4], w1[5]); a1h.w = pk_trunc(w1[6], w1[7]);
    a1l.x = pk_trunc(l1[0], l1[1]); a1l.y = pk_trunc(l1[2], l1[3]);
    a1l.z = pk_trunc(l1[4], l1[5]); a1l.w = pk_trunc(l1[6], l1[7]);
    a2h.x = pk_trunc(w2[0], w2[1]); a2h.y = pk_trunc(w2[2], w2[3]);
    a2h.z = pk_trunc(w2[4], w2[5]); a2h.w = pk_trunc(w2[6], w2[7]);
    a2l.x = pk_trunc(l2[0], l2[1]); a2l.y = pk_trunc(l2[2], l2[3]);
    a2l.z = pk_trunc(l2[4], l2[5]); a2l.w = pk_trunc(l2[6], l2[7]);
    const bf16x8 A1h = __builtin_bit_cast(bf16x8, a1h);
    const bf16x8 A1l = __builtin_bit_cast(bf16x8, a1l);
    const bf16x8 A2h = __builtin_bit_cast(bf16x8, a2h);
    const bf16x8 A2l = __builtin_bit_cast(bf16x8, a2l);

    // C-init constants as v2f pairs: z = K*(w_ih*x + b_ih+b_hh+rowsum(W_hh)).
    v2f kwih1a, kwih1b, kbias1a, kbias1b;
    v2f kwih2a, kwih2b, kbias2a, kbias2b;
#pragma unroll
    for (int reg = 0; reg < 4; ++reg) {
        const int r1 = 4 * g + reg;
        const int r2 = (16 + 4 * g + reg < RNN_H) ? (16 + 4 * g + reg) : (RNN_H - 1);
        float rs1 = 0.0f, rs2 = 0.0f;
#pragma unroll
        for (int c = 0; c < RNN_H; ++c) {
            rs1 += W_hh[r1 * RNN_H + c];
            rs2 += W_hh[r2 * RNN_H + c];
        }
        const float kw1 = KS * W_ih[r1];
        const float kb1 = KS * (b_ih[r1] + b_hh[r1] + rs1);
        const float kw2 = KS * W_ih[r2];
        const float kb2 = KS * (b_ih[r2] + b_hh[r2] + rs2);
        if (reg < 2) {
            kwih1a[reg] = kw1; kbias1a[reg] = kb1;
            kwih2a[reg] = kw2; kbias2a[reg] = kb2;
        } else {
            kwih1b[reg - 2] = kw1; kbias1b[reg - 2] = kb1;
            kwih2b[reg - 2] = kw2; kbias2b[reg - 2] = kb2;
        }
    }

    // State r = rcp(exp2(z)+1); r = 0.5 <=> h = 0. 0.5 is bf16-exact -> lo=0.
    float r10 = 0.5f, r11 = 0.5f, r12 = 0.5f, r13 = 0.5f;
    float r20 = 0.5f, r21 = 0.5f, r22 = 0.5f, r23 = 0.5f;
    i32x4 bh0;
    bh0.x = pk_trunc(0.5f, 0.5f); bh0.y = bh0.x; bh0.z = bh0.x; bh0.w = bh0.x;
    bf16x8 Bh = __builtin_bit_cast(bf16x8, bh0);
    i32x4 zz; zz.x = 0; zz.y = 0; zz.z = 0; zz.w = 0;
    bf16x8 Bl = __builtin_bit_cast(bf16x8, zz);

    const float4* x4 = (const float4*)(x + (size_t)(B0 + col) * RNN_T);

#define STEP(XS)                                                                 \
    do {                                                                         \
        const v2f xx2 = {(XS), (XS)};                                            \
        p2 t1, t2;                                                               \
        t1.a = __builtin_elementwise_fma(kwih1a, xx2, kbias1a);                  \
        t1.b = __builtin_elementwise_fma(kwih1b, xx2, kbias1b);                  \
        t2.a = __builtin_elementwise_fma(kwih2a, xx2, kbias2a);                  \
        t2.b = __builtin_elementwise_fma(kwih2b, xx2, kbias2b);                  \
        f32x4 acc1 = __builtin_bit_cast(f32x4, t1);                              \
        f32x4 acc2 = __builtin_bit_cast(f32x4, t2);                              \
        acc1 = __builtin_amdgcn_mfma_f32_16x16x32_bf16(A1h, Bh, acc1, 0, 0, 0);  \
        acc2 = __builtin_amdgcn_mfma_f32_16x16x32_bf16(A2h, Bh, acc2, 0, 0, 0);  \
        acc1 = __builtin_amdgcn_mfma_f32_16x16x32_bf16(A1l, Bh, acc1, 0, 0, 0);  \
        acc2 = __builtin_amdgcn_mfma_f32_16x16x32_bf16(A2l, Bh, acc2, 0, 0, 0);  \
        acc1 = __builtin_amdgcn_mfma_f32_16x16x32_bf16(A1h, Bl, acc1, 0, 0, 0);  \
        acc2 = __builtin_amdgcn_mfma_f32_16x16x32_bf16(A2h, Bl, acc2, 0, 0, 0);  \
        {                                                                        \
            const v2f one2 = {1.0f, 1.0f};                                       \
            v2f e01, e23, f01, f23;                                              \
            e01.x = __builtin_amdgcn_exp2f(acc1.x);                              \
            e01.y = __builtin_amdgcn_exp2f(acc1.y);                              \
            e23.x = __builtin_amdgcn_exp2f(acc1.z);                              \
            e23.y = __builtin_amdgcn_exp2f(acc1.w);                              \
            f01.x = __builtin_amdgcn_exp2f(acc2.x);                              \
            f01.y = __builtin_amdgcn_exp2f(acc2.y);                              \
            f23.x = __builtin_amdgcn_exp2f(acc2.z);                              \
            f23.y = __builtin_amdgcn_exp2f(acc2.w);                              \
            const v2f a01 = e01 + one2;  /* v_pk_add_f32 */                      \
            const v2f a23 = e23 + one2;                                          \
            const v2f b01 = f01 + one2;                                          \
            const v2f b23 = f23 + one2;                                          \
            r10 = __builtin_amdgcn_rcpf(a01.x);                                  \
            r11 = __builtin_amdgcn_rcpf(a01.y);                                  \
            r12 = __builtin_amdgcn_rcpf(a23.x);                                  \
            r13 = __builtin_amdgcn_rcpf(a23.y);                                  \
            r20 = __builtin_amdgcn_rcpf(b01.x);                                  \
            r21 = __builtin_amdgcn_rcpf(b01.y);                                  \
            r22 = __builtin_amdgcn_rcpf(b23.x);                                  \
            r23 = __builtin_amdgcn_rcpf(b23.y);                                  \
        }                                                                        \
        {                                                                        \
            i32x4 bh, bl;                                                        \
            bh.x = pk_trunc(r10, r11);                                           \
            bh.y = pk_trunc(r12, r13);                                           \
            bh.z = pk_trunc(r20, r21);                                           \
            bh.w = pk_trunc(r22, r23);                                           \
            v2f p0 = {r10, r11}, p1 = {r12, r13};                                \
            v2f p2_ = {r20, r21}, p3 = {r22, r23};                               \
            v2f h0 = {lo16f(bh.x), hi16f(bh.x)};                                 \
            v2f h1 = {lo16f(bh.y), hi16f(bh.y)};                                 \
            v2f h2 = {lo16f(bh.z), hi16f(bh.z)};                                 \
            v2f h3 = {lo16f(bh.w), hi16f(bh.w)};                                 \
            v2f q0 = p0 - h0, q1 = p1 - h1, q2 = p2_ - h2, q3 = p3 - h3;         \
            bl.x = pk_trunc(q0.x, q0.y);                                         \
            bl.y = pk_trunc(q1.x, q1.y);                                         \
            bl.z = pk_trunc(q2.x, q2.y);                                         \
            bl.w = pk_trunc(q3.x, q3.y);                                         \
            Bh = __builtin_bit_cast(bf16x8, bh);                                 \
            Bl = __builtin_bit_cast(bf16x8, bl);                                 \
        }                                                                        \
    } while (0)

    float4 xv = x4[0];
#pragma unroll 1
    for (int t4 = 0; t4 < NT4; ++t4) {
        const int tn = (t4 + 1 < NT4) ? (t4 + 1) : t4;
        const float4 xn = x4[tn];
        STEP(xv.x);
        STEP(xv.y);
        STEP(xv.z);
        STEP(xv.w);
        xv = xn;
    }
#undef STEP

    // Epilogue: h = 1-2r. Lane holds rows 4g..4g+3 (r1*) and, for g==0,
    // rows 16..19 (r2*); tile2 masked here (not in-loop). Reduce g-groups:
    // lanes l, l^16, l^32, l^48 share col.
    const float mk2 = (g == 0) ? 1.0f : 0.0f;
    const float ms2 = -2.0f * mk2;
    float p = fmaf(-2.0f, r10, 1.0f) * W_fc[4 * g + 0];
    p = fmaf(fmaf(-2.0f, r11, 1.0f), W_fc[4 * g + 1], p);
    p = fmaf(fmaf(-2.0f, r12, 1.0f), W_fc[4 * g + 2], p);
    p = fmaf(fmaf(-2.0f, r13, 1.0f), W_fc[4 * g + 3], p);
    p = fmaf(fmaf(ms2, r20, mk2), W_fc[16], p);
    p = fmaf(fmaf(ms2, r21, mk2), W_fc[17], p);
    p = fmaf(fmaf(ms2, r22, mk2), W_fc[18], p);
    p = fmaf(fmaf(ms2, r23, mk2), W_fc[19], p);
    p += __shfl_xor(p, 16, 64);
    p += __shfl_xor(p, 32, 64);
    if (lane < 16) {
        const float z = p + b_fc[0];
        const float e = __builtin_amdgcn_exp2f(-1.4426950408889634f * z);
        out[B0 + lane] = __builtin_amdgcn_rcpf(1.0f + e);
    }
}

extern "C" void kernel_launch(void* const* d_in, const int* in_sizes, int n_in,
                              void* d_out, int out_size, void* d_ws, size_t ws_size,
                              hipStream_t stream) {
    const float* x    = (const float*)d_in[0];
    const float* W_ih = (const float*)d_in[1];
    const float* W_hh = (const float*)d_in[2];
    const float* b_ih = (const float*)d_in[3];
    const float* b_hh = (const float*)d_in[4];
    const float* W_fc = (const float*)d_in[5];
    const float* b_fc = (const float*)d_in[6];
    float* out = (float*)d_out;

    const int threads = (RNN_B / 16) * 64;  // 65536 = 1024 waves = 1/SIMD
    const int block   = 256;
    rnn_fwd<<<threads / block, block, 0, stream>>>(x, W_ih, W_hh, b_ih, b_hh,
                                                   W_fc, b_fc, out);
}

// Round 12
// 485.650 us; speedup vs baseline: 1.2504x; 1.2504x over previous
//
#include <hip/hip_runtime.h>

// SimpleRNN: B=16384, T=2048, I=1, H=20, O=1, fp32.
//
// Round-16. r15 post-mortem: pk-merging was neutral (busy dropped, wall
// didn't) => currency is VALU lane-cycles + stalls, not inst slots.
// Structural fix: REBALANCED TILE2. Output row 16+g mapped to A-row 4g
// (other tile2 A-rows zero) => lane-group g owns rows K(g)={4g..4g+3,16+g}:
//  - act on 5 real elements (was 8, incl. 75%-garbage tile2 regs)
//  - balanced in-lane hi/lo supply lets the 3 correction terms
//    (Whi*hi, Wlo*hi, Whi*lo -- same math as r14) pack into TWO B-fragments
//    and 4 MFMAs total (was 6), 2-deep chains:
//      B_I(g)  = {hi[K(g)], lo[K(g)[0..2]]}          A_I  = Whi[.,K] / Whi
//      B_II(g) = {hi[K(g)], lo[K(g)[3..4]], 0}       A_II = Wlo[.,K] / Whi
//    coverage: union over g hits every k in {0..19} exactly once per term.
//  - epilogue: no masking; rows 16..19 held once each by groups 0..3.
// Step ~39 src-insts (was ~60): 5 init-fma + 4 MFMA + 5 exp2 + 3 add +
// 5 rcp + 14 pack + ~3 loop. Trans count 16 -> 10.
//
// rc-state folding kept: state r = rcp(exp2(z)+1); W_hh pre-scaled -2K,
// bias = K*(b_ih+b_hh+rowsum(W_hh)), W_ih by K (K=2*log2(e)); h=1-2r in
// epilogue. C-layout (verified r9): col=lane&15=batch, row=4*(lane>>4)+reg;
// A/B share the same (g,j)->k slot map (r9-established).
//
// 16 batches/wave -> 65536 threads = 1024 waves = 1 wave/SIMD, full chip.

#define RNN_T 2048
#define RNN_H 20
#define RNN_B 16384
#define NT4   (RNN_T / 4)

typedef float f32x4  __attribute__((ext_vector_type(4)));
typedef float v2f    __attribute__((ext_vector_type(2)));
typedef short bf16x8 __attribute__((ext_vector_type(8)));
typedef int   i32x4  __attribute__((ext_vector_type(4)));

// D = [bf16(b) : bf16(a)] by truncation; a lands in the LOW short (slot j0).
__device__ __forceinline__ int pk_trunc(float a, float b) {
    return __builtin_amdgcn_perm(__builtin_bit_cast(int, b),
                                 __builtin_bit_cast(int, a), 0x07060302);
}
__device__ __forceinline__ float trunc_bf(float a) {
    return __builtin_bit_cast(float,
                              (int)(__builtin_bit_cast(int, a) & 0xffff0000));
}
// Recover the two truncated f32 values from a packed [bf16:bf16] word.
__device__ __forceinline__ float lo16f(int w) {
    return __builtin_bit_cast(float, (int)(w << 16));
}
__device__ __forceinline__ float hi16f(int w) {
    return __builtin_bit_cast(float, (int)(w & (int)0xffff0000u));
}

__attribute__((amdgpu_flat_work_group_size(256, 256)))
__global__ void rnn_fwd(const float* __restrict__ x,
                        const float* __restrict__ W_ih,
                        const float* __restrict__ W_hh,
                        const float* __restrict__ b_ih,
                        const float* __restrict__ b_hh,
                        const float* __restrict__ W_fc,
                        const float* __restrict__ b_fc,
                        float* __restrict__ out) {
    const int gid  = blockIdx.x * blockDim.x + threadIdx.x;
    const int lane = threadIdx.x & 63;
    const int wid  = gid >> 6;        // global wave index
    const int B0   = wid * 16;        // this wave's batch block
    const int col  = lane & 15;       // batch slot / A-row m / B-col n
    const int g    = lane >> 4;       // k-block / C-row-block

    const float KS = 2.885390081777927f;  // 2*log2(e)
    const float WS = -2.0f * KS;          // W_hh scale

    // ---- Prologue: A fragments. Lane holds A-row m=col for both tiles.
    // Slot k-set for group g: K(g)[j] = (j<4) ? 4g+j : 16+g  (j=0..4).
    // Tile1: A-row m = output row m (0..15).
    // Tile2: A-row m = output row 16+m/4 if m%4==0, else ZERO.
    float whi[5], wlo[5], vhi[5], vlo[5];
#pragma unroll
    for (int j = 0; j < 5; ++j) {
        const int k  = (j < 4) ? (4 * g + j) : (16 + g);
        const float w = WS * W_hh[col * RNN_H + k];
        whi[j] = trunc_bf(w);
        wlo[j] = w - whi[j];
        const float w2 = ((col & 3) == 0)
                             ? WS * W_hh[(16 + (col >> 2)) * RNN_H + k]
                             : 0.0f;
        vhi[j] = trunc_bf(w2);
        vlo[j] = w2 - vhi[j];
    }
    // A_I:  j0..4 = Whi[K], j5..7 = Whi[K[0..2]]  (pairs with B_I's lo slots)
    // A_II: j0..4 = Wlo[K], j5..6 = Whi[K[3..4]], j7 = 0
    i32x4 ai1, aii1, ai2, aii2;
    ai1.x  = pk_trunc(whi[0], whi[1]); ai1.y  = pk_trunc(whi[2], whi[3]);
    ai1.z  = pk_trunc(whi[4], whi[0]); ai1.w  = pk_trunc(whi[1], whi[2]);
    aii1.x = pk_trunc(wlo[0], wlo[1]); aii1.y = pk_trunc(wlo[2], wlo[3]);
    aii1.z = pk_trunc(wlo[4], whi[3]); aii1.w = pk_trunc(whi[4], 0.0f);
    ai2.x  = pk_trunc(vhi[0], vhi[1]); ai2.y  = pk_trunc(vhi[2], vhi[3]);
    ai2.z  = pk_trunc(vhi[4], vhi[0]); ai2.w  = pk_trunc(vhi[1], vhi[2]);
    aii2.x = pk_trunc(vlo[0], vlo[1]); aii2.y = pk_trunc(vlo[2], vlo[3]);
    aii2.z = pk_trunc(vlo[4], vhi[3]); aii2.w = pk_trunc(vhi[4], 0.0f);
    const bf16x8 AI1  = __builtin_bit_cast(bf16x8, ai1);
    const bf16x8 AII1 = __builtin_bit_cast(bf16x8, aii1);
    const bf16x8 AI2  = __builtin_bit_cast(bf16x8, ai2);
    const bf16x8 AII2 = __builtin_bit_cast(bf16x8, aii2);

    // C-init: tile1 rows 4g+reg (f32x4); tile2 row 16+g (reg 0 only).
    f32x4 kwih1, kbias1;
#pragma unroll
    for (int reg = 0; reg < 4; ++reg) {
        const int r1 = 4 * g + reg;
        float rs = 0.0f;
#pragma unroll
        for (int c = 0; c < RNN_H; ++c) rs += W_hh[r1 * RNN_H + c];
        kwih1[reg]  = KS * W_ih[r1];
        kbias1[reg] = KS * (b_ih[r1] + b_hh[r1] + rs);
    }
    const int r2row = 16 + g;
    float rs2 = 0.0f;
#pragma unroll
    for (int c = 0; c < RNN_H; ++c) rs2 += W_hh[r2row * RNN_H + c];
    const float kwih2  = KS * W_ih[r2row];
    const float kbias2 = KS * (b_ih[r2row] + b_hh[r2row] + rs2);

    // State r = rcp(exp2(z)+1); r = 0.5 <=> h = 0 (bf16-exact, lo = 0).
    float r0 = 0.5f, r1 = 0.5f, r2 = 0.5f, r3 = 0.5f, r4 = 0.5f;
    i32x4 bi0, bii0;
    bi0.x = pk_trunc(0.5f, 0.5f); bi0.y = bi0.x;
    bi0.z = pk_trunc(0.5f, 0.0f); bi0.w = 0;
    bii0 = bi0;
    bf16x8 BI  = __builtin_bit_cast(bf16x8, bi0);
    bf16x8 BII = __builtin_bit_cast(bf16x8, bii0);

    const float4* x4 = (const float4*)(x + (size_t)(B0 + col) * RNN_T);

#define STEP(XS)                                                                 \
    do {                                                                         \
        f32x4 xx = {(XS), (XS), (XS), (XS)};                                     \
        f32x4 acc1 = __builtin_elementwise_fma(kwih1, xx, kbias1);               \
        f32x4 acc2 = {fmaf(kwih2, (XS), kbias2), 0.0f, 0.0f, 0.0f};              \
        acc1 = __builtin_amdgcn_mfma_f32_16x16x32_bf16(AII1, BII, acc1, 0, 0, 0);\
        acc2 = __builtin_amdgcn_mfma_f32_16x16x32_bf16(AII2, BII, acc2, 0, 0, 0);\
        acc1 = __builtin_amdgcn_mfma_f32_16x16x32_bf16(AI1, BI, acc1, 0, 0, 0);  \
        acc2 = __builtin_amdgcn_mfma_f32_16x16x32_bf16(AI2, BI, acc2, 0, 0, 0);  \
        {                                                                        \
            const v2f one2 = {1.0f, 1.0f};                                       \
            v2f e01, e23;                                                        \
            e01.x = __builtin_amdgcn_exp2f(acc1.x);                              \
            e01.y = __builtin_amdgcn_exp2f(acc1.y);                              \
            e23.x = __builtin_amdgcn_exp2f(acc1.z);                              \
            e23.y = __builtin_amdgcn_exp2f(acc1.w);                              \
            const float e4 = __builtin_amdgcn_exp2f(acc2.x);                     \
            const v2f a01 = e01 + one2;                                          \
            const v2f a23 = e23 + one2;                                          \
            const float a4 = e4 + 1.0f;                                          \
            r0 = __builtin_amdgcn_rcpf(a01.x);                                   \
            r1 = __builtin_amdgcn_rcpf(a01.y);                                   \
            r2 = __builtin_amdgcn_rcpf(a23.x);                                   \
            r3 = __builtin_amdgcn_rcpf(a23.y);                                   \
            r4 = __builtin_amdgcn_rcpf(a4);                                      \
        }                                                                        \
        {                                                                        \
            i32x4 bi, bii;                                                       \
            const int W0 = pk_trunc(r0, r1);                                     \
            const int W1 = pk_trunc(r2, r3);                                     \
            v2f p01 = {r0, r1}, p23 = {r2, r3};                                  \
            v2f t01 = {lo16f(W0), hi16f(W0)};                                    \
            v2f t23 = {lo16f(W1), hi16f(W1)};                                    \
            const v2f q01 = p01 - t01;   /* lo0, lo1 */                          \
            const v2f q23 = p23 - t23;   /* lo2, lo3 */                          \
            const float l4 = r4 - trunc_bf(r4);                                  \
            bi.x  = W0; bi.y  = W1;                                              \
            bi.z  = pk_trunc(r4, q01.x);        /* (hi4, lo0) */                 \
            bi.w  = pk_trunc(q01.y, q23.x);     /* (lo1, lo2) */                 \
            bii.x = W0; bii.y = W1;                                              \
            bii.z = pk_trunc(r4, q23.y);        /* (hi4, lo3) */                 \
            bii.w = pk_trunc(l4, 0.0f);         /* (lo4, 0)   */                 \
            BI  = __builtin_bit_cast(bf16x8, bi);                                \
            BII = __builtin_bit_cast(bf16x8, bii);                               \
        }                                                                        \
    } while (0)

    float4 xv = x4[0];
#pragma unroll 1
    for (int t4 = 0; t4 < NT4; ++t4) {
        const int tn = (t4 + 1 < NT4) ? (t4 + 1) : t4;
        const float4 xn = x4[tn];
        STEP(xv.x);
        STEP(xv.y);
        STEP(xv.z);
        STEP(xv.w);
        xv = xn;
    }
#undef STEP

    // Epilogue: h = 1-2r for rows K(g) = {4g..4g+3, 16+g} -- all real, no
    // masking. Reduce over g-groups (lanes l, l^16, l^32, l^48 share col).
    float p = fmaf(-2.0f, r0, 1.0f) * W_fc[4 * g + 0];
    p = fmaf(fmaf(-2.0f, r1, 1.0f), W_fc[4 * g + 1], p);
    p = fmaf(fmaf(-2.0f, r2, 1.0f), W_fc[4 * g + 2], p);
    p = fmaf(fmaf(-2.0f, r3, 1.0f), W_fc[4 * g + 3], p);
    p = fmaf(fmaf(-2.0f, r4, 1.0f), W_fc[16 + g], p);
    p += __shfl_xor(p, 16, 64);
    p += __shfl_xor(p, 32, 64);
    if (lane < 16) {
        const float z = p + b_fc[0];
        const float e = __builtin_amdgcn_exp2f(-1.4426950408889634f * z);
        out[B0 + lane] = __builtin_amdgcn_rcpf(1.0f + e);
    }
}

extern "C" void kernel_launch(void* const* d_in, const int* in_sizes, int n_in,
                              void* d_out, int out_size, void* d_ws, size_t ws_size,
                              hipStream_t stream) {
    const float* x    = (const float*)d_in[0];
    const float* W_ih = (const float*)d_in[1];
    const float* W_hh = (const float*)d_in[2];
    const float* b_ih = (const float*)d_in[3];
    const float* b_hh = (const float*)d_in[4];
    const float* W_fc = (const float*)d_in[5];
    const float* b_fc = (const float*)d_in[6];
    float* out = (float*)d_out;

    const int threads = (RNN_B / 16) * 64;  // 65536 = 1024 waves = 1/SIMD
    const int block   = 256;
    rnn_fwd<<<threads / block, block, 0, stream>>>(x, W_ih, W_hh, b_ih, b_hh,
                                                   W_fc, b_fc, out);
}